// Round 9
// baseline (334.557 us; speedup 1.0000x reference)
//
#include <hip/hip_runtime.h>
#include <hip/hip_bf16.h>

#define DIN  136
#define HH   128
#define NSEQ 256
#define NB   256

// fragment-order weight buffers (prep output, staged linearly to LDS)
#define W1F_SH (8 * 5 * 64 * 8)   // 20480 shorts = 40960 B  (8 tn, 5 kc, 64 ln, 8 j)
#define W2F_SH (8 * 4 * 64 * 8)   // 16384 shorts = 32768 B

typedef __attribute__((ext_vector_type(4))) float f32x4;
typedef __attribute__((ext_vector_type(8))) short bf16x8;

static __device__ __forceinline__ unsigned cvt2(float lo, float hi) {
    __hip_bfloat162 h = __float22bfloat162_rn(make_float2(lo, hi));
    return *(unsigned*)&h;
}
static __device__ __forceinline__ short f2bf1(float f) {
    __hip_bfloat16 h = __float2bfloat16(f);
    return *(short*)&h;
}

// ---------------------------------------------------------------------------
// Prep: weights pre-shuffled into MFMA A-fragment order (transposed layers):
// w1f[((tn*5+kc)*64+l)*8+j] = bf16(W1[k][n]), n = tn*16+(l&15),
// k = kc*32+(l>>4)*8+j, zero for k>=136. w2f analogous with 4 kc (K=128).
// In-kernel A-frag load is then one lane-linear ds_read_b128, conflict-free.
// ---------------------------------------------------------------------------
__global__ __launch_bounds__(256)
void prep_kernel(const float* __restrict__ W1, const float* __restrict__ W2,
                 short* __restrict__ w1f, short* __restrict__ w2f)
{
    const int nt = gridDim.x * 256;
    const int idx = blockIdx.x * 256 + threadIdx.x;
    for (int e = idx; e < W1F_SH; e += nt) {
        const int tn = e / 2560, r = e - tn * 2560;
        const int kc = r >> 9, r2 = r & 511, l = r2 >> 3, j = r2 & 7;
        const int n = tn * 16 + (l & 15);
        const int k = kc * 32 + (l >> 4) * 8 + j;
        w1f[e] = (k < DIN) ? f2bf1(W1[k * HH + n]) : (short)0;
    }
    for (int e = idx; e < W2F_SH; e += nt) {
        const int tn = e >> 11, r = e & 2047;
        const int kc = r >> 9, r2 = r & 511, l = r2 >> 3, j = r2 & 7;
        const int n = tn * 16 + (l & 15);
        const int k = kc * 32 + (l >> 4) * 8 + j;
        w2f[e] = f2bf1(W2[k * HH + n]);
    }
}

// ---------------------------------------------------------------------------
// Fused kernel v5 (operand-swapped, 2 blocks/query):
// grid 512, 512 threads (8 waves). Block = (query q, i-half). Each block
// computes ALL 256 scores (duplicated MLP, ~2us total) then half the lambdas.
// MLP per wave per mt-pass (mt=0,1): 16 data rows, transposed MFMA:
//   h1^T = W1^T (LDS A-frag) x X^T (features direct from global, B-frag)
//   -> lane holds h1[m = lane&15][n-subset]; in-register __shfl redistribution
//   -> h2^T = W2^T x h1^T; layer 3 via 2 shfl_xor. No feature/h1 LDS.
// LDS = fragment weights 72 KB + sp 4 KB + s_part 2 KB = 78 KB -> 2 blocks/CU.
// Only 2 barriers; waves drift freely through the MLP.
// ---------------------------------------------------------------------------
__global__ __launch_bounds__(512, 4)
void fused_kernel(const float* __restrict__ features,
                  const int*   __restrict__ labels,
                  const short* __restrict__ w1f,   // w2f contiguous after it
                  const float* __restrict__ b1, const float* __restrict__ b2,
                  const float* __restrict__ W3, const float* __restrict__ b3,
                  float* __restrict__ out)
{
    __shared__ __align__(16) char smem[79872];
    short* w1_lds = (short*)smem;                            // 40960 B
    short* w2_lds = (short*)(smem + 40960);                  // 32768 B
    float4* sp    = (float4*)(smem + 73728);                 // 4096 B
    float (*s_part)[128] = (float (*)[128])(smem + 77824);   // 2048 B

    const int t    = threadIdx.x;
    const int lane = t & 63;
    const int wave = t >> 6;          // 0..7
    const int l15  = lane & 15;
    const int kg2  = lane >> 4;       // 0..3 k-quarter

    // XCD swizzle: logical ids so the pair (2q,2q+1) shares an XCD (L2 reuse)
    const int bid     = blockIdx.x;
    const int logical = (bid >> 3) + (bid & 7) * 64;   // bijective on [0,512)
    const int q       = logical >> 1;
    const int ih      = (logical & 1) * 128;           // this block's i-half
    const long row0   = (long)q * NSEQ;

    // ---- stage fragment weights: one linear 73728 B copy (4608 uint4) ----
    {
        const uint4* src = (const uint4*)w1f;
        uint4* dst = (uint4*)smem;
#pragma unroll
        for (int m = 0; m < 9; ++m) dst[t + m * 512] = src[t + m * 512];
    }
    __syncthreads();

    const float log2e = 1.44269504088896f;
    const float b3v = b3[0];

    for (int mt = 0; mt < 2; ++mt) {
        const float* frow =
            features + (row0 + mt * 128 + wave * 16 + l15) * (long)DIN;

        // ---- layer 1 (transposed): D1[n][m], K = 4*32 + 8 tail ----
        f32x4 acc1[8];
#pragma unroll
        for (int tn = 0; tn < 8; ++tn)
#pragma unroll
            for (int qq = 0; qq < 4; ++qq)
                acc1[tn][qq] = b1[tn * 16 + kg2 * 4 + qq];
#pragma unroll
        for (int kc = 0; kc < 5; ++kc) {
            bf16x8 bfr;
            if (kc < 4 || kg2 == 0) {        // tail k=128..135 only from kg2==0
                const float* fp = frow + kc * 32 + kg2 * 8;
                const f32x4 g0 = *(const f32x4*)fp;
                const f32x4 g1 = *(const f32x4*)(fp + 4);
                union { bf16x8 v; unsigned u[4]; } bb;
                bb.u[0] = cvt2(g0.x, g0.y); bb.u[1] = cvt2(g0.z, g0.w);
                bb.u[2] = cvt2(g1.x, g1.y); bb.u[3] = cvt2(g1.z, g1.w);
                bfr = bb.v;
            } else {
                bfr = (bf16x8){0,0,0,0,0,0,0,0};   // w1f is 0 there too
            }
#pragma unroll
            for (int tn = 0; tn < 8; ++tn) {
                const bf16x8 afr =
                    *(const bf16x8*)&w1_lds[((tn * 5 + kc) * 64 + lane) * 8];
                acc1[tn] = __builtin_amdgcn_mfma_f32_16x16x32_bf16(
                    afr, bfr, acc1[tn], 0, 0, 0);
            }
        }

        // ---- relu + pack: p[tn*2+h] = bf16 pair at n = tn*16 + 4*kg2 + 2h ----
        unsigned p[16];
#pragma unroll
        for (int tn = 0; tn < 8; ++tn) {
            p[tn * 2 + 0] = cvt2(fmaxf(acc1[tn][0], 0.f), fmaxf(acc1[tn][1], 0.f));
            p[tn * 2 + 1] = cvt2(fmaxf(acc1[tn][2], 0.f), fmaxf(acc1[tn][3], 0.f));
        }

        // ---- layer 2 (transposed): B-frag assembled by shfl redistribution.
        // Lane needs h1[m][k = kc*32 + kg2*8 + j]; sources: quarter pair
        // q0 = 2*(kg2&1), q0+1 (same m = l15); tn_src = 2kc + (kg2>>1). ----
        f32x4 acc2[8];
#pragma unroll
        for (int tn = 0; tn < 8; ++tn)
#pragma unroll
            for (int qq = 0; qq < 4; ++qq)
                acc2[tn][qq] = b2[tn * 16 + kg2 * 4 + qq];
        const int s0 = l15 + 32 * (kg2 & 1);
        const int s1 = s0 + 16;
        const bool hiTn = (kg2 >> 1) & 1;
#pragma unroll
        for (int kc = 0; kc < 4; ++kc) {
            const unsigned a0 = __shfl((int)p[4 * kc + 0], s0);
            const unsigned c0 = __shfl((int)p[4 * kc + 2], s0);
            const unsigned a1 = __shfl((int)p[4 * kc + 1], s0);
            const unsigned c1 = __shfl((int)p[4 * kc + 3], s0);
            const unsigned a2 = __shfl((int)p[4 * kc + 0], s1);
            const unsigned c2 = __shfl((int)p[4 * kc + 2], s1);
            const unsigned a3 = __shfl((int)p[4 * kc + 1], s1);
            const unsigned c3 = __shfl((int)p[4 * kc + 3], s1);
            union { bf16x8 v; unsigned u[4]; } bb;
            bb.u[0] = hiTn ? c0 : a0;
            bb.u[1] = hiTn ? c1 : a1;
            bb.u[2] = hiTn ? c2 : a2;
            bb.u[3] = hiTn ? c3 : a3;
#pragma unroll
            for (int tn = 0; tn < 8; ++tn) {
                const bf16x8 afr =
                    *(const bf16x8*)&w2_lds[((tn * 4 + kc) * 64 + lane) * 8];
                acc2[tn] = __builtin_amdgcn_mfma_f32_16x16x32_bf16(
                    afr, bb.v, acc2[tn], 0, 0, 0);
            }
        }

        // ---- layer 3: score[m] = b3 + sum_n relu(h2[n][m]) * W3[n] ----
        float partial = 0.f;
#pragma unroll
        for (int tn = 0; tn < 8; ++tn)
#pragma unroll
            for (int qq = 0; qq < 4; ++qq)
                partial += fmaxf(acc2[tn][qq], 0.f) * W3[tn * 16 + kg2 * 4 + qq];
        partial += __shfl_xor(partial, 16, 64);
        partial += __shfl_xor(partial, 32, 64);
        if (lane < 16) {
            const int row = mt * 128 + wave * 16 + lane;
            const float s = partial + b3v;
            const int lab = labels[row0 + row];
            const float g = 0.5f * exp2f((float)lab);          // 0.5 folded
            const float disc = 1.f / (1.f + log2f(1.f + s));
            sp[row] = make_float4(s * log2e, g, disc, 0.f);    // log2e folded
        }
    }
    __syncthreads();

    // ---- pairwise lambdas for this block's i-half: i = ih + (t&127),
    //      jg = t>>7 covers 64 j each ----
    {
        const int i  = ih + (t & 127);
        const int jg = t >> 7;
        const float4 me = sp[i];
        const float sci = me.x, gi = me.y, di = me.z;
        float accum = 0.f;
        const int j0 = jg * 64;
#pragma unroll 8
        for (int jj = 0; jj < 64; ++jj) {
            const float4 o = sp[j0 + jj];
            const float dg = o.y - gi;                         // (gj-gi)/2
            const float e  = exp2f(o.x - sci);                 // exp(sj-si)
            const float r  = __builtin_amdgcn_rcpf(1.f + e);   // sigmoid(si-sj)
            const float dmax = (sci > o.x) ? di : o.z;         // disc of max
            const float dn = fabsf(dg) * dmax;                 // 0 when li==lj
            const float w  = (dg < 0.f) ? r : (r - 1.f);
            accum += dn * w;
        }
        s_part[jg][t & 127] = accum;
    }
    __syncthreads();
    if (t < 128)
        out[row0 + ih + t] = s_part[0][t] + s_part[1][t] +
                             s_part[2][t] + s_part[3][t];
}

// ---------------------------------------------------------------------------
extern "C" void kernel_launch(void* const* d_in, const int* in_sizes, int n_in,
                              void* d_out, int out_size, void* d_ws, size_t ws_size,
                              hipStream_t stream)
{
    const float* features = (const float*)d_in[0];
    const int*   labels   = (const int*)d_in[1];
    const float* W1 = (const float*)d_in[2];
    const float* b1 = (const float*)d_in[3];
    const float* W2 = (const float*)d_in[4];
    const float* b2 = (const float*)d_in[5];
    const float* W3 = (const float*)d_in[6];
    const float* b3 = (const float*)d_in[7];

    short* w1f = (short*)d_ws;             // fragment-order W1 (zero-padded K)
    short* w2f = w1f + W1F_SH;             // fragment-order W2 (contiguous)
    float* out = (float*)d_out;

    prep_kernel<<<64, 256, 0, stream>>>(W1, W2, w1f, w2f);
    fused_kernel<<<NB * 2, 512, 0, stream>>>(
        features, labels, w1f, b1, b2, W3, b3, out);
}

// Round 10
// 221.959 us; speedup vs baseline: 1.5073x; 1.5073x over previous
//
#include <hip/hip_runtime.h>
#include <hip/hip_bf16.h>

#define DIN  136
#define HH   128
#define NSEQ 256
#define NB   256

// fragment-order weight buffers (prep output, staged linearly to LDS)
#define W1F_SH (8 * 5 * 64 * 8)   // 20480 shorts = 40960 B  (8 tn, 5 kc, 64 ln, 8 j)
#define W2F_SH (8 * 4 * 64 * 8)   // 16384 shorts = 32768 B

typedef __attribute__((ext_vector_type(4))) float    f32x4;
typedef __attribute__((ext_vector_type(4))) unsigned u32x4;
typedef __attribute__((ext_vector_type(8))) short    bf16x8;

static __device__ __forceinline__ unsigned cvt2(float lo, float hi) {
    __hip_bfloat162 h = __float22bfloat162_rn(make_float2(lo, hi));
    return *(unsigned*)&h;
}
static __device__ __forceinline__ short f2bf1(float f) {
    __hip_bfloat16 h = __float2bfloat16(f);
    return *(short*)&h;
}

// ---------------------------------------------------------------------------
// Prep: weights pre-shuffled into MFMA A-fragment order (transposed layers):
// w1f[((tn*5+kc)*64+l)*8+j] = bf16(W1[k][n]), n = tn*16+(l&15),
// k = kc*32+(l>>4)*8+j, zero for k>=136. w2f analogous with 4 kc (K=128).
// ---------------------------------------------------------------------------
__global__ __launch_bounds__(256)
void prep_kernel(const float* __restrict__ W1, const float* __restrict__ W2,
                 short* __restrict__ w1f, short* __restrict__ w2f)
{
    const int nt = gridDim.x * 256;
    const int idx = blockIdx.x * 256 + threadIdx.x;
    for (int e = idx; e < W1F_SH; e += nt) {
        const int tn = e / 2560, r = e - tn * 2560;
        const int kc = r >> 9, r2 = r & 511, l = r2 >> 3, j = r2 & 7;
        const int n = tn * 16 + (l & 15);
        const int k = kc * 32 + (l >> 4) * 8 + j;
        w1f[e] = (k < DIN) ? f2bf1(W1[k * HH + n]) : (short)0;
    }
    for (int e = idx; e < W2F_SH; e += nt) {
        const int tn = e >> 11, r = e & 2047;
        const int kc = r >> 9, r2 = r & 511, l = r2 >> 3, j = r2 & 7;
        const int n = tn * 16 + (l & 15);
        const int k = kc * 32 + (l >> 4) * 8 + j;
        w2f[e] = f2bf1(W2[k * HH + n]);
    }
}

// ---------------------------------------------------------------------------
// Fused kernel v6 = v5 with register pressure fixed:
//  - __launch_bounds__(512, 1): no VGPR cap -> no scratch spills
//  - __builtin_bit_cast instead of unions (SROA-safe)
//  - layer 2/3 processed in two tn-halves (acc2 = 4 tiles live, not 8)
// Structure unchanged (verified correct in r9): grid 512 = (query, i-half),
// 8 waves; transposed MFMA, features direct from global, h1 via in-register
// shfl redistribution; LDS = weights 72KB + sp 4KB + s_part 2KB.
// ---------------------------------------------------------------------------
__global__ __launch_bounds__(512, 1)
void fused_kernel(const float* __restrict__ features,
                  const int*   __restrict__ labels,
                  const short* __restrict__ w1f,   // w2f contiguous after it
                  const float* __restrict__ b1, const float* __restrict__ b2,
                  const float* __restrict__ W3, const float* __restrict__ b3,
                  float* __restrict__ out)
{
    __shared__ __align__(16) char smem[79872];
    short* w1_lds = (short*)smem;                            // 40960 B
    short* w2_lds = (short*)(smem + 40960);                  // 32768 B
    float4* sp    = (float4*)(smem + 73728);                 // 4096 B
    float (*s_part)[128] = (float (*)[128])(smem + 77824);   // 2048 B

    const int t    = threadIdx.x;
    const int lane = t & 63;
    const int wave = t >> 6;          // 0..7
    const int l15  = lane & 15;
    const int kg2  = lane >> 4;       // 0..3 k-quarter

    // XCD swizzle: pair (2q,2q+1) shares an XCD (features L2 reuse)
    const int bid     = blockIdx.x;
    const int logical = (bid >> 3) + (bid & 7) * 64;   // bijective on [0,512)
    const int q       = logical >> 1;
    const int ih      = (logical & 1) * 128;           // this block's i-half
    const long row0   = (long)q * NSEQ;

    // ---- stage fragment weights: one linear 73728 B copy (4608 uint4) ----
    {
        const uint4* src = (const uint4*)w1f;
        uint4* dst = (uint4*)smem;
#pragma unroll
        for (int m = 0; m < 9; ++m) dst[t + m * 512] = src[t + m * 512];
    }
    __syncthreads();

    const float log2e = 1.44269504088896f;
    const float b3v = b3[0];

    for (int mt = 0; mt < 2; ++mt) {
        const float* frow =
            features + (row0 + mt * 128 + wave * 16 + l15) * (long)DIN;

        // ---- layer 1 (transposed): D1[n][m], K = 4*32 + 8 tail ----
        f32x4 acc1[8];
#pragma unroll
        for (int tn = 0; tn < 8; ++tn)
#pragma unroll
            for (int qq = 0; qq < 4; ++qq)
                acc1[tn][qq] = b1[tn * 16 + kg2 * 4 + qq];
#pragma unroll
        for (int kc = 0; kc < 5; ++kc) {
            bf16x8 bfr;
            if (kc < 4 || kg2 == 0) {        // tail k=128..135 only from kg2==0
                const float* fp = frow + kc * 32 + kg2 * 8;
                const f32x4 g0 = *(const f32x4*)fp;
                const f32x4 g1 = *(const f32x4*)(fp + 4);
                u32x4 bu;
                bu[0] = cvt2(g0.x, g0.y); bu[1] = cvt2(g0.z, g0.w);
                bu[2] = cvt2(g1.x, g1.y); bu[3] = cvt2(g1.z, g1.w);
                bfr = __builtin_bit_cast(bf16x8, bu);
            } else {
                bfr = (bf16x8){0,0,0,0,0,0,0,0};   // w1f is 0 there too
            }
#pragma unroll
            for (int tn = 0; tn < 8; ++tn) {
                const bf16x8 afr =
                    *(const bf16x8*)&w1_lds[((tn * 5 + kc) * 64 + lane) * 8];
                acc1[tn] = __builtin_amdgcn_mfma_f32_16x16x32_bf16(
                    afr, bfr, acc1[tn], 0, 0, 0);
            }
        }

        // ---- relu + pack: p[tn*2+h] = bf16 pair at n = tn*16 + 4*kg2 + 2h ----
        unsigned p[16];
#pragma unroll
        for (int tn = 0; tn < 8; ++tn) {
            p[tn * 2 + 0] = cvt2(fmaxf(acc1[tn][0], 0.f), fmaxf(acc1[tn][1], 0.f));
            p[tn * 2 + 1] = cvt2(fmaxf(acc1[tn][2], 0.f), fmaxf(acc1[tn][3], 0.f));
        }

        // ---- layer 2+3 (transposed) in two tn-halves: acc2 = 4 tiles live.
        // B-frag by shfl redistribution (same math as r9, verified):
        // s0 = l15 + 32*(kg2&1), s1 = s0+16, hi/lo word pick by kg2>>1. ----
        float partial = 0.f;
        const int s0 = l15 + 32 * (kg2 & 1);
        const int s1 = s0 + 16;
        const bool hiTn = (kg2 >> 1) & 1;
        for (int th = 0; th < 2; ++th) {
            f32x4 acc2[4];
#pragma unroll
            for (int tn = 0; tn < 4; ++tn)
#pragma unroll
                for (int qq = 0; qq < 4; ++qq)
                    acc2[tn][qq] = b2[(th * 4 + tn) * 16 + kg2 * 4 + qq];
#pragma unroll
            for (int kc = 0; kc < 4; ++kc) {
                const unsigned a0 = __shfl((int)p[4 * kc + 0], s0);
                const unsigned c0 = __shfl((int)p[4 * kc + 2], s0);
                const unsigned a1 = __shfl((int)p[4 * kc + 1], s0);
                const unsigned c1 = __shfl((int)p[4 * kc + 3], s0);
                const unsigned a2 = __shfl((int)p[4 * kc + 0], s1);
                const unsigned c2 = __shfl((int)p[4 * kc + 2], s1);
                const unsigned a3 = __shfl((int)p[4 * kc + 1], s1);
                const unsigned c3 = __shfl((int)p[4 * kc + 3], s1);
                u32x4 bu;
                bu[0] = hiTn ? c0 : a0;
                bu[1] = hiTn ? c1 : a1;
                bu[2] = hiTn ? c2 : a2;
                bu[3] = hiTn ? c3 : a3;
                const bf16x8 bfr = __builtin_bit_cast(bf16x8, bu);
#pragma unroll
                for (int tn = 0; tn < 4; ++tn) {
                    const bf16x8 afr = *(const bf16x8*)
                        &w2_lds[(((th * 4 + tn) * 4 + kc) * 64 + lane) * 8];
                    acc2[tn] = __builtin_amdgcn_mfma_f32_16x16x32_bf16(
                        afr, bfr, acc2[tn], 0, 0, 0);
                }
            }
#pragma unroll
            for (int tn = 0; tn < 4; ++tn)
#pragma unroll
                for (int qq = 0; qq < 4; ++qq)
                    partial += fmaxf(acc2[tn][qq], 0.f) *
                               W3[(th * 4 + tn) * 16 + kg2 * 4 + qq];
        }

        // ---- layer 3 reduce + pack row ----
        partial += __shfl_xor(partial, 16, 64);
        partial += __shfl_xor(partial, 32, 64);
        if (lane < 16) {
            const int row = mt * 128 + wave * 16 + lane;
            const float s = partial + b3v;
            const int lab = labels[row0 + row];
            const float g = 0.5f * exp2f((float)lab);          // 0.5 folded
            const float disc = 1.f / (1.f + log2f(1.f + s));
            sp[row] = make_float4(s * log2e, g, disc, 0.f);    // log2e folded
        }
    }
    __syncthreads();

    // ---- pairwise lambdas for this block's i-half: i = ih + (t&127),
    //      jg = t>>7 covers 64 j each ----
    {
        const int i  = ih + (t & 127);
        const int jg = t >> 7;
        const float4 me = sp[i];
        const float sci = me.x, gi = me.y, di = me.z;
        float accum = 0.f;
        const int j0 = jg * 64;
#pragma unroll 8
        for (int jj = 0; jj < 64; ++jj) {
            const float4 o = sp[j0 + jj];
            const float dg = o.y - gi;                         // (gj-gi)/2
            const float e  = exp2f(o.x - sci);                 // exp(sj-si)
            const float r  = __builtin_amdgcn_rcpf(1.f + e);   // sigmoid(si-sj)
            const float dmax = (sci > o.x) ? di : o.z;         // disc of max
            const float dn = fabsf(dg) * dmax;                 // 0 when li==lj
            const float w  = (dg < 0.f) ? r : (r - 1.f);
            accum += dn * w;
        }
        s_part[jg][t & 127] = accum;
    }
    __syncthreads();
    if (t < 128)
        out[row0 + ih + t] = s_part[0][t] + s_part[1][t] +
                             s_part[2][t] + s_part[3][t];
}

// ---------------------------------------------------------------------------
extern "C" void kernel_launch(void* const* d_in, const int* in_sizes, int n_in,
                              void* d_out, int out_size, void* d_ws, size_t ws_size,
                              hipStream_t stream)
{
    const float* features = (const float*)d_in[0];
    const int*   labels   = (const int*)d_in[1];
    const float* W1 = (const float*)d_in[2];
    const float* b1 = (const float*)d_in[3];
    const float* W2 = (const float*)d_in[4];
    const float* b2 = (const float*)d_in[5];
    const float* W3 = (const float*)d_in[6];
    const float* b3 = (const float*)d_in[7];

    short* w1f = (short*)d_ws;             // fragment-order W1 (zero-padded K)
    short* w2f = w1f + W1F_SH;             // fragment-order W2 (contiguous)
    float* out = (float*)d_out;

    prep_kernel<<<64, 256, 0, stream>>>(W1, W2, w1f, w2f);
    fused_kernel<<<NB * 2, 512, 0, stream>>>(
        features, labels, w1f, b1, b2, W3, b3, out);
}

// Round 12
// 112.139 us; speedup vs baseline: 2.9834x; 1.9793x over previous
//
#include <hip/hip_runtime.h>
#include <hip/hip_bf16.h>

#define DIN  136
#define HH   128
#define NSEQ 256
#define NB   256
#define ST   136          // LDS/weight row stride (elements)

typedef __attribute__((ext_vector_type(4))) float f32x4;
typedef __attribute__((ext_vector_type(8))) short bf16x8;

typedef const __attribute__((address_space(1))) unsigned int gas_u32;
typedef __attribute__((address_space(3))) unsigned int las_u32;

static __device__ __forceinline__ unsigned cvt2(float lo, float hi) {
    __hip_bfloat162 h = __float22bfloat162_rn(make_float2(lo, hi));
    return *(unsigned*)&h;
}
static __device__ __forceinline__ short f2bf1(float f) {
    __hip_bfloat16 h = __float2bfloat16(f);
    return *(short*)&h;
}
static __device__ __forceinline__ void gld_lds16(const void* g, void* l) {
    __builtin_amdgcn_global_load_lds((gas_u32*)g, (las_u32*)l, 16, 0, 0);
}

// ---------------------------------------------------------------------------
// Prep (2048 blocks, throughput-bound): bf16 weights in LDS-final layout
// (w1s[n][k]=W1[k][n] [128][136]; w2s same from W2, zero-padded k>=128) AND
// all features converted fp32->bf16 linear (LDS-final). Fused then stages
// everything by pure DMA, zero conversion work.
// ---------------------------------------------------------------------------
__global__ __launch_bounds__(256)
void prep_kernel(const float* __restrict__ features,
                 const float* __restrict__ W1, const float* __restrict__ W2,
                 short* __restrict__ wbuf,      // [2][128][136] bf16
                 unsigned* __restrict__ fbf)    // features bf16, as u32 pairs
{
    const int nt = gridDim.x * 256;
    const int idx = blockIdx.x * 256 + threadIdx.x;
    for (int e = idx; e < HH * ST; e += nt) {
        const int n = e / ST, k = e - n * ST;          // k < 136: all real
        wbuf[e] = f2bf1(W1[k * HH + n]);
    }
    for (int e = idx; e < HH * ST; e += nt) {
        const int n = e / ST, k = e - n * ST;
        wbuf[HH * ST + e] = (k < HH) ? f2bf1(W2[k * HH + n]) : (short)0;
    }
    const f32x4* src = (const f32x4*)features;         // 65536*34 f32x4
    uint2* dst = (uint2*)fbf;
    const int total = NB * NSEQ * DIN / 4;
    for (int i = idx; i < total; i += nt) {
        const f32x4 v = src[i];
        uint2 p;
        p.x = cvt2(v.x, v.y);
        p.y = cvt2(v.z, v.w);
        dst[i] = p;
    }
}

// ---------------------------------------------------------------------------
// Fused kernel v7b = r11 with the LDS overflow FIXED: layout needs
// 139264 (a_lds+w1+w2) + 4096 (sp) + 4096 (s_part[4][256]) = 147456 B.
// (r11 declared 145408 -> s_part[2..3] were out of bounds -> garbage sums.)
// Structure: r7-verified compute (full-LDS MFMA operands, 16 waves,
// wave-private h1 rows, no inter-layer barrier) + async global_load_lds
// DMA staging of pre-converted bf16 (no cvt, no VGPR round trip).
// ---------------------------------------------------------------------------
__global__ __launch_bounds__(1024, 4)
void fused_kernel(const short* __restrict__ wbuf,   // [2][128][136] bf16
                  const short* __restrict__ fbf,    // [65536][136] bf16
                  const int*   __restrict__ labels,
                  const float* __restrict__ b1, const float* __restrict__ b2,
                  const float* __restrict__ W3, const float* __restrict__ b3,
                  float* __restrict__ out)
{
    __shared__ __align__(16) char smem[147456];
    short* a_lds  = (short*)smem;                            // [256][136] 69632 B
    short* w1_lds = (short*)(smem + 69632);                  // [128][136] 34816 B
    short* w2_lds = (short*)(smem + 104448);                 // [128][136] 34816 B
    float4* sp    = (float4*)(smem + 139264);                // 4096 B
    float (*s_part)[NSEQ] = (float (*)[NSEQ])(smem + 143360);  // 4096 B

    const int t    = threadIdx.x;
    const int lane = t & 63;
    const int wv   = t >> 6;      // 0..15
    const int l15  = lane & 15;
    const int l4   = lane >> 4;
    const long row0 = (long)blockIdx.x * NSEQ;     // query = blockIdx.x

    // ---- stage via DMA: features slab (68 KiB-chunks) + weights (68) ----
    {
        const char* fsrc = (const char*)fbf + (size_t)blockIdx.x * 69632;
        const char* wsrc = (const char*)wbuf;
        const int lo = lane * 16;
        for (int c = wv; c < 68; c += 16)
            gld_lds16(fsrc + c * 1024 + lo, smem + c * 1024 + lo);
        for (int c = wv; c < 68; c += 16)
            gld_lds16(wsrc + c * 1024 + lo, smem + 69632 + c * 1024 + lo);
    }
    __syncthreads();   // drains vmcnt (DMA) before anyone reads LDS

    const int arow = (wv * 16 + l15) * ST;

    // ---- layer 1: h1 = relu(A @ W1 + b1), K = 4*32 + 8 tail ----
    f32x4 acc[8];
#pragma unroll
    for (int tn = 0; tn < 8; ++tn) {
        const float bv = b1[tn * 16 + l15];
        acc[tn] = (f32x4){bv, bv, bv, bv};
    }
    for (int kc = 0; kc < 4; ++kc) {
        const int kb = kc * 32 + l4 * 8;
        const bf16x8 afr = *(const bf16x8*)&a_lds[arow + kb];
        bf16x8 bfr[8];
#pragma unroll
        for (int tn = 0; tn < 8; ++tn)
            bfr[tn] = *(const bf16x8*)&w1_lds[(tn * 16 + l15) * ST + kb];
#pragma unroll
        for (int tn = 0; tn < 8; ++tn)
            acc[tn] = __builtin_amdgcn_mfma_f32_16x16x32_bf16(afr, bfr[tn], acc[tn], 0, 0, 0);
    }
    {   // K-tail: cols 128..135, only the l4==0 k-group contributes
        bf16x8 afr = (bf16x8){0,0,0,0,0,0,0,0};
        bf16x8 bfr[8];
#pragma unroll
        for (int tn = 0; tn < 8; ++tn) bfr[tn] = (bf16x8){0,0,0,0,0,0,0,0};
        if (l4 == 0) {
            afr = *(const bf16x8*)&a_lds[arow + 128];
#pragma unroll
            for (int tn = 0; tn < 8; ++tn)
                bfr[tn] = *(const bf16x8*)&w1_lds[(tn * 16 + l15) * ST + 128];
        }
#pragma unroll
        for (int tn = 0; tn < 8; ++tn)
            acc[tn] = __builtin_amdgcn_mfma_f32_16x16x32_bf16(afr, bfr[tn], acc[tn], 0, 0, 0);
    }

    // ---- relu(h1) -> bf16 into the wave's OWN rows (no barrier needed).
    //      C/D layout: row = l4*4+j, col = l15  [m89/m91]. ----
#pragma unroll
    for (int tn = 0; tn < 8; ++tn) {
        const int col = tn * 16 + l15;
#pragma unroll
        for (int j = 0; j < 4; ++j)
            a_lds[(wv * 16 + l4 * 4 + j) * ST + col] = f2bf1(fmaxf(acc[tn][j], 0.f));
    }

    // ---- layer 2: h2 = relu(h1 @ W2 + b2), K = 128 ----
    f32x4 acc2[8];
#pragma unroll
    for (int tn = 0; tn < 8; ++tn) {
        const float bv = b2[tn * 16 + l15];
        acc2[tn] = (f32x4){bv, bv, bv, bv};
    }
    for (int kc = 0; kc < 4; ++kc) {
        const int kb = kc * 32 + l4 * 8;
        const bf16x8 afr = *(const bf16x8*)&a_lds[arow + kb];
        bf16x8 bfr[8];
#pragma unroll
        for (int tn = 0; tn < 8; ++tn)
            bfr[tn] = *(const bf16x8*)&w2_lds[(tn * 16 + l15) * ST + kb];
#pragma unroll
        for (int tn = 0; tn < 8; ++tn)
            acc2[tn] = __builtin_amdgcn_mfma_f32_16x16x32_bf16(afr, bfr[tn], acc2[tn], 0, 0, 0);
    }

    // ---- layer 3 + per-row pack {s*log2e, 0.5*gain, disc} into sp ----
    {
        float w3v[8];
#pragma unroll
        for (int tn = 0; tn < 8; ++tn) w3v[tn] = W3[tn * 16 + l15];
        const float b3v = b3[0];
#pragma unroll
        for (int j = 0; j < 4; ++j) {
            float p = 0.f;
#pragma unroll
            for (int tn = 0; tn < 8; ++tn)
                p += fmaxf(acc2[tn][j], 0.f) * w3v[tn];
            p += __shfl_xor(p, 1, 64);
            p += __shfl_xor(p, 2, 64);
            p += __shfl_xor(p, 4, 64);
            p += __shfl_xor(p, 8, 64);
            if (l15 == 0) {
                const int row = wv * 16 + l4 * 4 + j;
                const float s = p + b3v;
                const int lab = labels[row0 + row];
                const float g = 0.5f * exp2f((float)lab);      // 0.5 folded
                const float disc = 1.f / (1.f + log2f(1.f + s));
                sp[row] = make_float4(s * 1.44269504088896f,   // log2e folded
                                      g, disc, 0.f);
            }
        }
    }
    __syncthreads();

    // ---- pairwise lambdas: i = t&255, jg = t>>8 (64 j each) ----
    {
        const int i  = t & (NSEQ - 1);
        const int jg = t >> 8;
        const float4 me = sp[i];
        const float sci = me.x, gi = me.y, di = me.z;
        float accum = 0.f;
        const int j0 = jg * 64;
#pragma unroll 8
        for (int jj = 0; jj < 64; ++jj) {
            const float4 o = sp[j0 + jj];
            const float dg = o.y - gi;                         // (gj-gi)/2
            const float e  = exp2f(o.x - sci);                 // exp(sj-si)
            const float r  = __builtin_amdgcn_rcpf(1.f + e);   // sigmoid(si-sj)
            const float dmax = (sci > o.x) ? di : o.z;         // disc of max
            const float dn = fabsf(dg) * dmax;                 // 0 when li==lj
            const float w  = (dg < 0.f) ? r : (r - 1.f);
            accum += dn * w;
        }
        s_part[jg][t & 255] = accum;
    }
    __syncthreads();
    {
        const int i = t & (NSEQ - 1);
        if ((t >> 8) == 0)
            out[row0 + i] = s_part[0][i] + s_part[1][i] +
                            s_part[2][i] + s_part[3][i];
    }
}

// ---------------------------------------------------------------------------
extern "C" void kernel_launch(void* const* d_in, const int* in_sizes, int n_in,
                              void* d_out, int out_size, void* d_ws, size_t ws_size,
                              hipStream_t stream)
{
    const float* features = (const float*)d_in[0];
    const int*   labels   = (const int*)d_in[1];
    const float* W1 = (const float*)d_in[2];
    const float* b1 = (const float*)d_in[3];
    const float* W2 = (const float*)d_in[4];
    const float* b2 = (const float*)d_in[5];
    const float* W3 = (const float*)d_in[6];
    const float* b3 = (const float*)d_in[7];

    short*    wbuf = (short*)d_ws;                  // 69632 B weight block
    unsigned* fbf  = (unsigned*)(wbuf + 2 * HH * ST);  // 17.8 MB bf16 features
    float*    out  = (float*)d_out;

    prep_kernel<<<2048, 256, 0, stream>>>(features, W1, W2, wbuf, fbf);
    fused_kernel<<<NB, 1024, 0, stream>>>(
        wbuf, (const short*)fbf, labels, b1, b2, W3, b3, out);
}